// Round 6
// baseline (541.318 us; speedup 1.0000x reference)
//
#include <hip/hip_runtime.h>
#include <hip/hip_cooperative_groups.h>
#include <cstdint>

namespace cg = cooperative_groups;
typedef unsigned int uint;

#define BSHIFT 9          // 512 nodes per coarse bucket
#define MAXB 256          // supports N up to 131072
#define TILE 4096         // scatter tile = 256 threads x 16 edges
#define EPT 16
#define SORT_CAP 12288    // per-bucket cap (mean ~8163, >50 sigma headroom)

__device__ __forceinline__ float leaky02(float x) { return x > 0.f ? x : 0.2f * x; }
__device__ __forceinline__ float bflo(uint u) { return __uint_as_float(u << 16); }
__device__ __forceinline__ float bfhi(uint u) { return __uint_as_float(u & 0xffff0000u); }

__device__ __forceinline__ uint pack_bf16x2(float a, float b) {
    uint ua = __float_as_uint(a), ub = __float_as_uint(b);
    ua += 0x7fffu + ((ua >> 16) & 1u);
    ub += 0x7fffu + ((ub >> 16) & 1u);
    return (ua >> 16) | (ub & 0xffff0000u);
}

// ---------------------------------------------------------------------------
// mega_csr (cooperative): init + linear + count + scan + scatter + sort.
// Phases separated by grid.sync(). 391 blocks x 256 threads, 56 KB LDS.
// ---------------------------------------------------------------------------
__global__ __launch_bounds__(256) void mega_csr(
    const float* __restrict__ x, const float* __restrict__ W,
    const float* __restrict__ att_s, const float* __restrict__ att_d,
    uint* __restrict__ h, float* __restrict__ a_src, float* __restrict__ a_dst,
    int N, const int* __restrict__ esrc, const int* __restrict__ edst, int E, int B,
    int* __restrict__ bcnt, int* __restrict__ bbase, int* __restrict__ cursor,
    uint* __restrict__ pairs, int* __restrict__ sorted, int* __restrict__ offsets,
    float* __restrict__ sums, float* __restrict__ sumsq) {
    cg::grid_group grid = cg::this_grid();
    __shared__ __align__(16) int smemi[14336];  // 56 KB, reused per phase
    int tid = threadIdx.x;

    // ---- P0: zero-init (block 0) ----
    if (blockIdx.x == 0) {
        bcnt[tid] = 0;
        if (tid < 128) { sums[tid] = 0.f; sumsq[tid] = 0.f; }
    }

    // ---- P1: linear. One wave per node row ----
    {
        int lane = tid & 63, wid = tid >> 6;
        for (int g = blockIdx.x; g * 4 < N; g += gridDim.x) {
            int n = g * 4 + wid;
            if (n < N) {
                const float* xr = x + (size_t)n * 16;
                float xv = xr[lane & 15];
                float acc0 = 0.f, acc1 = 0.f;
#pragma unroll
                for (int k = 0; k < 16; k++) {
                    float xk = __shfl(xv, k);
                    float2 w = ((const float2*)(W + k * 128))[lane];
                    acc0 += xk * w.x;
                    acc1 += xk * w.y;
                }
                h[(size_t)n * 64 + lane] = pack_bf16x2(acc0, acc1);
                float2 as = ((const float2*)att_s)[lane];
                float2 ad = ((const float2*)att_d)[lane];
                float ps = acc0 * as.x + acc1 * as.y;
                float pd = acc0 * ad.x + acc1 * ad.y;
#pragma unroll
                for (int off = 8; off >= 1; off >>= 1) {
                    ps += __shfl_xor(ps, off);
                    pd += __shfl_xor(pd, off);
                }
                if ((lane & 15) == 0) {
                    a_src[n * 4 + (lane >> 4)] = ps;
                    a_dst[n * 4 + (lane >> 4)] = pd;
                }
            }
        }
    }
    grid.sync();

    // ---- P2: coarse-bucket histogram ----
    {
        int* lc = smemi;
        lc[tid] = 0;
        __syncthreads();
        for (int i = blockIdx.x * 256 + tid; i < E; i += gridDim.x * 256)
            atomicAdd(&lc[edst[i] >> BSHIFT], 1);
        __syncthreads();
        if (lc[tid]) atomicAdd(&bcnt[tid], lc[tid]);
    }
    grid.sync();

    // ---- P3: bucket scan (block 0) ----
    if (blockIdx.x == 0) {
        int* sA = smemi;
        int* sB = smemi + 256;
        int v = (tid < B) ? bcnt[tid] : 0;
        int* a = sA; int* b = sB;
        a[tid] = v;
        __syncthreads();
        for (int off = 1; off < 256; off <<= 1) {
            b[tid] = a[tid] + (tid >= off ? a[tid - off] : 0);
            __syncthreads();
            int* t = a; a = b; b = t;
        }
        if (tid < B) {
            int ex = a[tid] - v;
            bbase[tid] = ex;
            cursor[tid] = ex;
        }
        if (tid == 0) bbase[B] = E;
    }
    grid.sync();

    // ---- P4: LDS-staged scatter into coarse buckets (packed words) ----
    {
        int t0 = blockIdx.x * TILE;
        if (t0 < E) {
            int* tileCnt  = smemi;
            int* tileCnt2 = smemi + 256;
            int* tileOff  = smemi + 512;
            int* gbase    = smemi + 768;
            int* sA       = smemi + 1024;
            int* sB       = smemi + 1280;
            uint* lp      = (uint*)(smemi + 1536);
            unsigned char* lb = (unsigned char*)(smemi + 1536 + TILE);
            tileCnt[tid] = 0;
            tileCnt2[tid] = 0;
            __syncthreads();
            int dreg[EPT], sreg[EPT];
#pragma unroll
            for (int j = 0; j < EPT; j++) {
                int idx = t0 + j * 256 + tid;
                if (idx < E) {
                    dreg[j] = edst[idx];
                    sreg[j] = esrc[idx];
                    atomicAdd(&tileCnt[dreg[j] >> BSHIFT], 1);
                } else dreg[j] = -1;
            }
            __syncthreads();
            int* a = sA; int* b = sB;
            a[tid] = tileCnt[tid];
            __syncthreads();
            for (int off = 1; off < 256; off <<= 1) {
                b[tid] = a[tid] + (tid >= off ? a[tid - off] : 0);
                __syncthreads();
                int* t = a; a = b; b = t;
            }
            tileOff[tid] = a[tid] - tileCnt[tid];
            if (tileCnt[tid] > 0) gbase[tid] = atomicAdd(&cursor[tid], tileCnt[tid]);
            __syncthreads();
#pragma unroll
            for (int j = 0; j < EPT; j++) {
                if (dreg[j] >= 0) {
                    int bk = dreg[j] >> BSHIFT;
                    int r = atomicAdd(&tileCnt2[bk], 1);
                    int pos = tileOff[bk] + r;
                    lp[pos] = ((uint)sreg[j] << BSHIFT) | (uint)(dreg[j] & 511);
                    lb[pos] = (unsigned char)bk;
                }
            }
            __syncthreads();
            int tot = min(TILE, E - t0);
            for (int k = tid; k < tot; k += 256) {
                int bk = lb[k];
                pairs[gbase[bk] + (k - tileOff[bk])] = lp[k];
            }
        }
    }
    grid.sync();

    // ---- P5: per-bucket counting sort -> sorted[] + offsets[] ----
    if (blockIdx.x < (uint)B) {
        int b = blockIdx.x;
        int n0 = b << BSHIFT;
        int nn = min(512, N - n0);
        int ebase = bbase[b];
        int ecnt = bbase[b + 1] - ebase;
        if (ecnt > SORT_CAP) ecnt = SORT_CAP;
        int* cnt  = smemi;
        int* off0 = smemi + 512;
        int* sA   = smemi + 1024;
        int* sB   = smemi + 1536;
        int* lsrc = smemi + 2048;
        cnt[tid] = 0; cnt[tid + 256] = 0;
        __syncthreads();
        for (int k = tid; k < ecnt; k += 256)
            atomicAdd(&cnt[pairs[ebase + k] & 511], 1);
        __syncthreads();
        int* a = sA; int* bb = sB;
        a[tid] = cnt[tid];
        a[tid + 256] = cnt[tid + 256];
        __syncthreads();
        for (int off = 1; off < 512; off <<= 1) {
            bb[tid] = a[tid] + (tid >= off ? a[tid - off] : 0);
            int i2 = tid + 256;
            bb[i2] = a[i2] + (i2 >= off ? a[i2 - off] : 0);
            __syncthreads();
            int* t = a; a = bb; bb = t;
        }
        off0[tid] = a[tid] - cnt[tid];
        off0[tid + 256] = a[tid + 256] - cnt[tid + 256];
        __syncthreads();
        cnt[tid] = 0; cnt[tid + 256] = 0;
        __syncthreads();
        for (int k = tid; k < ecnt; k += 256) {
            uint p = pairs[ebase + k];
            int ln = p & 511;
            int r = atomicAdd(&cnt[ln], 1);
            lsrc[off0[ln] + r] = (int)(p >> BSHIFT);
        }
        __syncthreads();
        for (int k = tid; k < ecnt; k += 256) sorted[ebase + k] = lsrc[k];
        for (int t2 = tid; t2 < nn; t2 += 256) offsets[n0 + t2] = ebase + off0[t2];
        if (b == 0 && tid == 0) offsets[N] = E;
    }
}

// ---------------------------------------------------------------------------
// GAT aggregation: one wave per dst; 32 lanes x 4 channels (uint2), two edges
// per wave (half-waves own even/odd edges), merged via shfl_xor(32).
// ---------------------------------------------------------------------------
__global__ void k_gat(const int* __restrict__ offsets, const int* __restrict__ sorted,
                      const uint* __restrict__ h, const float* __restrict__ a_src,
                      const float* __restrict__ a_dst, const float* __restrict__ bias,
                      uint* __restrict__ hagg, int N) {
    int nb = gridDim.x;
    int g = nb >> 3;
    int bi = blockIdx.x;
    int blk = (bi < (g << 3)) ? ((bi & 7) * g + (bi >> 3)) : bi;
    int lane = threadIdx.x & 63;
    int d = blk * 4 + (threadIdx.x >> 6);
    if (d >= N) return;
    int base = offsets[d];
    int deg = offsets[d + 1] - base;
    int half = lane >> 5;
    int l32 = lane & 31;
    int head = l32 >> 3;
    float adsth = a_dst[d * 4 + head];

    float4 acc = make_float4(0.f, 0.f, 0.f, 0.f);
    float sum = 0.f;
    if (half == 0) {  // self loop
        float w = __expf(leaky02(a_src[d * 4 + head] + adsth));
        uint2 u = ((const uint2*)(h + (size_t)d * 64))[l32];
        sum = w;
        acc.x = w * bflo(u.x); acc.y = w * bfhi(u.x);
        acc.z = w * bflo(u.y); acc.w = w * bfhi(u.y);
    }
    int i = half;
    while (i + 2 < deg) {
        int s0 = sorted[base + i];
        int s1 = sorted[base + i + 2];
        float w0 = __expf(leaky02(a_src[s0 * 4 + head] + adsth));
        float w1 = __expf(leaky02(a_src[s1 * 4 + head] + adsth));
        uint2 u0 = ((const uint2*)(h + (size_t)s0 * 64))[l32];
        uint2 u1 = ((const uint2*)(h + (size_t)s1 * 64))[l32];
        sum += w0 + w1;
        acc.x += w0 * bflo(u0.x) + w1 * bflo(u1.x);
        acc.y += w0 * bfhi(u0.x) + w1 * bfhi(u1.x);
        acc.z += w0 * bflo(u0.y) + w1 * bflo(u1.y);
        acc.w += w0 * bfhi(u0.y) + w1 * bfhi(u1.y);
        i += 4;
    }
    if (i < deg) {
        int s0 = sorted[base + i];
        float w0 = __expf(leaky02(a_src[s0 * 4 + head] + adsth));
        uint2 u0 = ((const uint2*)(h + (size_t)s0 * 64))[l32];
        sum += w0;
        acc.x += w0 * bflo(u0.x);
        acc.y += w0 * bfhi(u0.x);
        acc.z += w0 * bflo(u0.y);
        acc.w += w0 * bfhi(u0.y);
    }
    sum += __shfl_xor(sum, 32);
    acc.x += __shfl_xor(acc.x, 32);
    acc.y += __shfl_xor(acc.y, 32);
    acc.z += __shfl_xor(acc.z, 32);
    acc.w += __shfl_xor(acc.w, 32);
    if (half == 0) {
        float inv = 1.f / sum;
        float4 bg = ((const float4*)bias)[l32];
        uint2 pu;
        pu.x = pack_bf16x2(acc.x * inv + bg.x, acc.y * inv + bg.y);
        pu.y = pack_bf16x2(acc.z * inv + bg.z, acc.w * inv + bg.w);
        ((uint2*)(hagg + (size_t)d * 64))[l32] = pu;
    }
}

// ---------------------------------------------------------------------------
// k_mlpbn (cooperative, 256 blocks): BN column stats + grid.sync + MLP.
// ---------------------------------------------------------------------------
__global__ __launch_bounds__(256) void k_mlpbn(
    const uint* __restrict__ hagg, const int* __restrict__ lut,
    float* __restrict__ sums, float* __restrict__ sumsq,
    const float* __restrict__ gamma, const float* __restrict__ beta,
    const float* __restrict__ W1, const float* __restrict__ b1,
    const float* __restrict__ W2, const float* __restrict__ b2,
    float* __restrict__ out, int N, int nlut) {
    cg::grid_group grid = cg::this_grid();
    int t = threadIdx.x;
    // ---- phase A: column sums / sums of squares ----
    {
        int cgp = t & 31, rs = t >> 5;
        float4 s = make_float4(0.f, 0.f, 0.f, 0.f), q = make_float4(0.f, 0.f, 0.f, 0.f);
        for (int n = blockIdx.x * 8 + rs; n < N; n += gridDim.x * 8) {
            uint2 u = ((const uint2*)(hagg + (size_t)n * 64))[cgp];
            float v0 = bflo(u.x), v1 = bfhi(u.x), v2 = bflo(u.y), v3 = bfhi(u.y);
            s.x += v0; s.y += v1; s.z += v2; s.w += v3;
            q.x += v0 * v0; q.y += v1 * v1; q.z += v2 * v2; q.w += v3 * v3;
        }
        __shared__ float4 ls[256], lq[256];
        ls[t] = s; lq[t] = q;
        __syncthreads();
        if (t < 32) {
            float4 S = ls[t], Q = lq[t];
            for (int r = 1; r < 8; r++) {
                float4 a = ls[t + r * 32], b = lq[t + r * 32];
                S.x += a.x; S.y += a.y; S.z += a.z; S.w += a.w;
                Q.x += b.x; Q.y += b.y; Q.z += b.z; Q.w += b.w;
            }
            atomicAdd(&sums[t * 4 + 0], S.x);
            atomicAdd(&sums[t * 4 + 1], S.y);
            atomicAdd(&sums[t * 4 + 2], S.z);
            atomicAdd(&sums[t * 4 + 3], S.w);
            atomicAdd(&sumsq[t * 4 + 0], Q.x);
            atomicAdd(&sumsq[t * 4 + 1], Q.y);
            atomicAdd(&sumsq[t * 4 + 2], Q.z);
            atomicAdd(&sumsq[t * 4 + 3], Q.w);
        }
    }
    grid.sync();
    // ---- phase B: per-LUT-node BN + ReLU + MLP ----
    {
        int lane = t & 63, wid = t >> 6;
        __shared__ float v[4][128];
        float invN = 1.f / (float)N;
        for (int base = blockIdx.x * 4; base < nlut; base += gridDim.x * 4) {
            int blk = base + wid;
            if (blk < nlut) {
                int node = lut[blk];
                uint u = hagg[(size_t)node * 64 + lane];
                int c0 = 2 * lane, c1 = c0 + 1;
                float mean = sums[c0] * invN;
                float var = sumsq[c0] * invN - mean * mean;
                float val = (bflo(u) - mean) / sqrtf(var + 1e-5f) * gamma[c0] + beta[c0];
                v[wid][c0] = fmaxf(val, 0.f);
                mean = sums[c1] * invN;
                var = sumsq[c1] * invN - mean * mean;
                val = (bfhi(u) - mean) / sqrtf(var + 1e-5f) * gamma[c1] + beta[c1];
                v[wid][c1] = fmaxf(val, 0.f);
            }
            __syncthreads();
            float r = 0.f;
            if (blk < nlut && lane < 32) {
                float z = b1[lane];
                for (int c = 0; c < 128; c++) z += v[wid][c] * W1[c * 32 + lane];
                z = z > 0.f ? z : 0.01f * z;
                r = z * W2[lane];
            }
#pragma unroll
            for (int off = 16; off >= 1; off >>= 1) r += __shfl_xor(r, off);
            if (blk < nlut && lane == 0) out[blk] = r + b2[0];
            __syncthreads();
        }
    }
}

// ---------------------------------------------------------------------------
extern "C" void kernel_launch(void* const* d_in, const int* in_sizes, int n_in,
                              void* d_out, int out_size, void* d_ws, size_t ws_size,
                              hipStream_t stream) {
    const float* x     = (const float*)d_in[0];
    const int*   edges = (const int*)d_in[1];
    const int*   lut   = (const int*)d_in[2];
    const float* W_lin = (const float*)d_in[3];
    const float* att_s = (const float*)d_in[4];
    const float* att_d = (const float*)d_in[5];
    const float* bias  = (const float*)d_in[6];
    const float* gamma = (const float*)d_in[7];
    const float* beta  = (const float*)d_in[8];
    const float* W1    = (const float*)d_in[9];
    const float* b1    = (const float*)d_in[10];
    const float* W2    = (const float*)d_in[11];
    const float* b2    = (const float*)d_in[12];

    int N = in_sizes[0] / 16;
    int E = in_sizes[1] / 2;
    int nlut = in_sizes[2];
    int B = (N + 511) >> BSHIFT;

    const int* esrc = edges;
    const int* edst = edges + E;

    char* ws = (char*)d_ws;
    size_t off = 0;
    auto alloc = [&](size_t bytes) -> void* {
        void* p = ws + off;
        off += (bytes + 255) & ~(size_t)255;
        return p;
    };
    uint*  h       = (uint*)alloc((size_t)N * 64 * 4);   // bf16x2 [N,128]
    uint*  hagg    = (uint*)alloc((size_t)N * 64 * 4);   // bf16x2 [N,128]
    float* a_src   = (float*)alloc((size_t)N * 4 * 4);
    float* a_dst   = (float*)alloc((size_t)N * 4 * 4);
    int*   offsets = (int*)alloc((size_t)(N + 1) * 4);
    int*   sorted  = (int*)alloc((size_t)E * 4);
    uint*  pairs   = (uint*)alloc((size_t)E * 4);
    int*   bbase   = (int*)alloc((size_t)(MAXB + 1) * 4);
    int*   cursor  = (int*)alloc((size_t)MAXB * 4);
    int*   bcnt    = (int*)alloc((size_t)MAXB * 4);
    float* sums    = (float*)alloc(128 * 4);
    float* sumsq   = (float*)alloc(128 * 4);

    int TC = (E + TILE - 1) / TILE;
    int gridCsr = TC > B ? TC : B;   // 391 for N=100k, E=1.6M (<= 512 capacity)
    float* outp = (float*)d_out;

    {
        void* args[] = {&x, &W_lin, &att_s, &att_d, &h, &a_src, &a_dst, &N,
                        &esrc, &edst, &E, &B, &bcnt, &bbase, &cursor,
                        &pairs, &sorted, &offsets, &sums, &sumsq};
        hipLaunchCooperativeKernel((void*)mega_csr, dim3(gridCsr), dim3(256),
                                   args, 0, stream);
    }
    k_gat<<<(N + 3) / 4, 256, 0, stream>>>(offsets, sorted, h, a_src, a_dst, bias, hagg, N);
    {
        void* args[] = {&hagg, &lut, &sums, &sumsq, &gamma, &beta,
                        &W1, &b1, &W2, &b2, &outp, &N, &nlut};
        hipLaunchCooperativeKernel((void*)k_mlpbn, dim3(256), dim3(256),
                                   args, 0, stream);
    }
}

// Round 7
// 305.111 us; speedup vs baseline: 1.7742x; 1.7742x over previous
//
#include <hip/hip_runtime.h>
#include <cstdint>

typedef unsigned int uint;

#define BSHIFT 9          // 512 nodes per coarse bucket
#define MAXB 256          // supports N up to 131072 (and src < 2^23 for packing)
#define TILE 4096         // kb_scatter tile
#define SCAT_T 512
#define SORT_T 512
#define SORT_CAP 12288    // per-bucket cap (mean ~8163, >50 sigma headroom)

__device__ __forceinline__ float leaky02(float x) { return x > 0.f ? x : 0.2f * x; }
__device__ __forceinline__ float bflo(uint u) { return __uint_as_float(u << 16); }
__device__ __forceinline__ float bfhi(uint u) { return __uint_as_float(u & 0xffff0000u); }

__device__ __forceinline__ uint pack_bf16x2(float a, float b) {
    uint ua = __float_as_uint(a), ub = __float_as_uint(b);
    ua += 0x7fffu + ((ua >> 16) & 1u);
    ub += 0x7fffu + ((ub >> 16) & 1u);
    return (ua >> 16) | (ub & 0xffff0000u);
}

// ---------------------------------------------------------------------------
// Kernel A: h = x @ W_lin (bf16x2), a_src/a_dst per head. Block 0 zero-inits.
// ---------------------------------------------------------------------------
__global__ void k_linear(const float* __restrict__ x, const float* __restrict__ W,
                         const float* __restrict__ att_s, const float* __restrict__ att_d,
                         uint* __restrict__ h, float* __restrict__ a_src,
                         float* __restrict__ a_dst, int N,
                         int* __restrict__ bcnt, float* __restrict__ sums,
                         float* __restrict__ sumsq, int* __restrict__ done) {
    if (blockIdx.x == 0) {
        int t = threadIdx.x;
        bcnt[t] = 0;
        if (t < 128) { sums[t] = 0.f; sumsq[t] = 0.f; }
        if (t == 0) *done = 0;
    }
    int lane = threadIdx.x & 63;
    int n = blockIdx.x * 4 + (threadIdx.x >> 6);
    if (n >= N) return;
    const float* xr = x + (size_t)n * 16;
    float xv = xr[lane & 15];  // lanes 0-15 hold the row; rest duplicates
    float acc0 = 0.f, acc1 = 0.f;
#pragma unroll
    for (int k = 0; k < 16; k++) {
        float xk = __shfl(xv, k);
        float2 w = ((const float2*)(W + k * 128))[lane];
        acc0 += xk * w.x;
        acc1 += xk * w.y;
    }
    h[(size_t)n * 64 + lane] = pack_bf16x2(acc0, acc1);
    float2 as = ((const float2*)att_s)[lane];
    float2 ad = ((const float2*)att_d)[lane];
    float ps = acc0 * as.x + acc1 * as.y;
    float pd = acc0 * ad.x + acc1 * ad.y;
#pragma unroll
    for (int off = 8; off >= 1; off >>= 1) {
        ps += __shfl_xor(ps, off);
        pd += __shfl_xor(pd, off);
    }
    if ((lane & 15) == 0) {
        a_src[n * 4 + (lane >> 4)] = ps;
        a_dst[n * 4 + (lane >> 4)] = pd;
    }
}

// ---------------------------------------------------------------------------
// CSR level 1: coarse histogram + fused bucket scan in the last-done block.
// ---------------------------------------------------------------------------
__global__ void kb_count(const int* __restrict__ dst, int E, int B,
                         int* __restrict__ bcnt, int* __restrict__ done,
                         int* __restrict__ bbase, int* __restrict__ cursor) {
    __shared__ int lc[MAXB];
    __shared__ int sA[MAXB], sB[MAXB];
    __shared__ int isLast;
    int tid = threadIdx.x;
    lc[tid] = 0;
    __syncthreads();
    for (int i = blockIdx.x * blockDim.x + tid; i < E; i += gridDim.x * blockDim.x)
        atomicAdd(&lc[dst[i] >> BSHIFT], 1);
    __syncthreads();
    if (lc[tid]) atomicAdd(&bcnt[tid], lc[tid]);
    __threadfence();
    __syncthreads();
    if (tid == 0) isLast = (atomicAdd(done, 1) == gridDim.x - 1) ? 1 : 0;
    __syncthreads();
    if (!isLast) return;
    int v = (tid < B) ? __hip_atomic_load(&bcnt[tid], __ATOMIC_RELAXED,
                                          __HIP_MEMORY_SCOPE_AGENT) : 0;
    int* a = sA; int* b = sB;
    a[tid] = v;
    __syncthreads();
    for (int off = 1; off < MAXB; off <<= 1) {
        b[tid] = a[tid] + (tid >= off ? a[tid - off] : 0);
        __syncthreads();
        int* t = a; a = b; b = t;
    }
    if (tid < B) {
        int ex = a[tid] - v;
        bbase[tid] = ex;
        cursor[tid] = ex;
    }
    if (tid == 0) bbase[B] = E;
}

// ---------------------------------------------------------------------------
// CSR level 1 scatter: LDS-staged binning into coarse buckets, packed words.
// code = (src << 9) | (dst & 511)
// ---------------------------------------------------------------------------
__global__ void kb_scatter(const int* __restrict__ src, const int* __restrict__ dst, int E,
                           int* __restrict__ cursor, uint* __restrict__ pairs) {
    __shared__ int tileCnt[MAXB], tileCnt2[MAXB], tileOff[MAXB], gbase[MAXB];
    __shared__ int sA[MAXB], sB[MAXB];
    __shared__ uint lp[TILE];
    __shared__ unsigned char lb[TILE];
    int tid = threadIdx.x;  // 512
    int t0 = blockIdx.x * TILE;
    if (tid < MAXB) { tileCnt[tid] = 0; tileCnt2[tid] = 0; }
    __syncthreads();
    int dreg[8], sreg[8];
#pragma unroll
    for (int j = 0; j < 8; j++) {
        int idx = t0 + j * SCAT_T + tid;
        if (idx < E) {
            dreg[j] = dst[idx];
            sreg[j] = src[idx];
            atomicAdd(&tileCnt[dreg[j] >> BSHIFT], 1);
        } else dreg[j] = -1;
    }
    __syncthreads();
    int* a = sA; int* b = sB;
    if (tid < MAXB) a[tid] = tileCnt[tid];
    __syncthreads();
    for (int off = 1; off < MAXB; off <<= 1) {
        if (tid < MAXB) b[tid] = a[tid] + (tid >= off ? a[tid - off] : 0);
        __syncthreads();
        int* t = a; a = b; b = t;
    }
    if (tid < MAXB) {
        tileOff[tid] = a[tid] - tileCnt[tid];
        if (tileCnt[tid] > 0) gbase[tid] = atomicAdd(&cursor[tid], tileCnt[tid]);
    }
    __syncthreads();
#pragma unroll
    for (int j = 0; j < 8; j++) {
        if (dreg[j] >= 0) {
            int bk = dreg[j] >> BSHIFT;
            int r = atomicAdd(&tileCnt2[bk], 1);
            int pos = tileOff[bk] + r;
            lp[pos] = ((uint)sreg[j] << BSHIFT) | (uint)(dreg[j] & 511);
            lb[pos] = (unsigned char)bk;
        }
    }
    __syncthreads();
    int tot = min(TILE, E - t0);
    for (int k = tid; k < tot; k += SCAT_T) {
        int bk = lb[k];
        pairs[gbase[bk] + (k - tileOff[bk])] = lp[k];
    }
}

// ---------------------------------------------------------------------------
// CSR level 2: per-bucket exact counting sort; emits sorted[] + offsets[].
// ---------------------------------------------------------------------------
__global__ void kb_sort(const uint* __restrict__ pairs, const int* __restrict__ bbase,
                        int N, int E,
                        int* __restrict__ sorted, int* __restrict__ offsets) {
    __shared__ int cnt[512], off0[512], sA[512], sB[512];
    __shared__ int lsrc[SORT_CAP];
    int tid = threadIdx.x;  // 512
    int b = blockIdx.x;
    int n0 = b << BSHIFT;
    int nn = min(512, N - n0);
    int ebase = bbase[b];
    int ecnt = bbase[b + 1] - ebase;
    if (ecnt > SORT_CAP) ecnt = SORT_CAP;
    cnt[tid] = 0;
    __syncthreads();
    for (int k = tid; k < ecnt; k += SORT_T)
        atomicAdd(&cnt[pairs[ebase + k] & 511], 1);
    __syncthreads();
    int* a = sA; int* bb = sB;
    a[tid] = cnt[tid];
    __syncthreads();
    for (int off = 1; off < 512; off <<= 1) {
        bb[tid] = a[tid] + (tid >= off ? a[tid - off] : 0);
        __syncthreads();
        int* t = a; a = bb; bb = t;
    }
    off0[tid] = a[tid] - cnt[tid];
    __syncthreads();
    cnt[tid] = 0;
    __syncthreads();
    for (int k = tid; k < ecnt; k += SORT_T) {
        uint p = pairs[ebase + k];
        int ln = p & 511;
        int r = atomicAdd(&cnt[ln], 1);
        lsrc[off0[ln] + r] = (int)(p >> BSHIFT);
    }
    __syncthreads();
    for (int k = tid; k < ecnt; k += SORT_T) sorted[ebase + k] = lsrc[k];
    if (tid < nn) offsets[n0 + tid] = ebase + off0[tid];
    if (b == 0 && tid == 0) offsets[N] = E;
}

// ---------------------------------------------------------------------------
// GAT aggregation: one wave per dst. 16 lanes x 8 channels (uint4); 4 edge
// groups (q = lane>>4) walk interleaved edges; merged via shfl_xor(16,32).
// Per 4 edges: 1 dwordx4 h-load (4 rows = 1KB), 1 sorted, 1 a_src, 1 expf.
// ---------------------------------------------------------------------------
__global__ void k_gat(const int* __restrict__ offsets, const int* __restrict__ sorted,
                      const uint* __restrict__ h, const float* __restrict__ a_src,
                      const float* __restrict__ a_dst, const float* __restrict__ bias,
                      uint* __restrict__ hagg, int N) {
    int nb = gridDim.x;
    int g = nb >> 3;
    int bi = blockIdx.x;
    int blk = (bi < (g << 3)) ? ((bi & 7) * g + (bi >> 3)) : bi;
    int lane = threadIdx.x & 63;
    int d = blk * 4 + (threadIdx.x >> 6);
    if (d >= N) return;
    int base = offsets[d];
    int deg = offsets[d + 1] - base;
    int q = lane >> 4;      // edge group 0..3
    int l16 = lane & 15;    // channel group: 8 channels (uint4)
    int head = l16 >> 2;
    float adsth = a_dst[d * 4 + head];

    float acc[8] = {0.f, 0.f, 0.f, 0.f, 0.f, 0.f, 0.f, 0.f};
    float sum = 0.f;
    if (q == 0) {   // self loop
        float w = __expf(leaky02(a_src[d * 4 + head] + adsth));
        uint4 u = ((const uint4*)(h + (size_t)d * 64))[l16];
        sum = w;
        acc[0] = w * bflo(u.x); acc[1] = w * bfhi(u.x);
        acc[2] = w * bflo(u.y); acc[3] = w * bfhi(u.y);
        acc[4] = w * bflo(u.z); acc[5] = w * bfhi(u.z);
        acc[6] = w * bflo(u.w); acc[7] = w * bfhi(u.w);
    }
    int i = q;
    while (i + 4 < deg) {   // unroll x2: edges i and i+4
        int s0 = sorted[base + i];
        int s1 = sorted[base + i + 4];
        float w0 = __expf(leaky02(a_src[s0 * 4 + head] + adsth));
        float w1 = __expf(leaky02(a_src[s1 * 4 + head] + adsth));
        uint4 u0 = ((const uint4*)(h + (size_t)s0 * 64))[l16];
        uint4 u1 = ((const uint4*)(h + (size_t)s1 * 64))[l16];
        sum += w0 + w1;
        acc[0] += w0 * bflo(u0.x) + w1 * bflo(u1.x);
        acc[1] += w0 * bfhi(u0.x) + w1 * bfhi(u1.x);
        acc[2] += w0 * bflo(u0.y) + w1 * bflo(u1.y);
        acc[3] += w0 * bfhi(u0.y) + w1 * bfhi(u1.y);
        acc[4] += w0 * bflo(u0.z) + w1 * bflo(u1.z);
        acc[5] += w0 * bfhi(u0.z) + w1 * bfhi(u1.z);
        acc[6] += w0 * bflo(u0.w) + w1 * bflo(u1.w);
        acc[7] += w0 * bfhi(u0.w) + w1 * bfhi(u1.w);
        i += 8;
    }
    if (i < deg) {
        int s0 = sorted[base + i];
        float w0 = __expf(leaky02(a_src[s0 * 4 + head] + adsth));
        uint4 u0 = ((const uint4*)(h + (size_t)s0 * 64))[l16];
        sum += w0;
        acc[0] += w0 * bflo(u0.x);
        acc[1] += w0 * bfhi(u0.x);
        acc[2] += w0 * bflo(u0.y);
        acc[3] += w0 * bfhi(u0.y);
        acc[4] += w0 * bflo(u0.z);
        acc[5] += w0 * bfhi(u0.z);
        acc[6] += w0 * bflo(u0.w);
        acc[7] += w0 * bfhi(u0.w);
    }
    // merge the 4 edge groups
#pragma unroll
    for (int off = 16; off <= 32; off <<= 1) {
        sum += __shfl_xor(sum, off);
#pragma unroll
        for (int j = 0; j < 8; j++) acc[j] += __shfl_xor(acc[j], off);
    }
    if (q == 0) {
        float inv = 1.f / sum;
        float4 b0 = ((const float4*)bias)[2 * l16];
        float4 b1 = ((const float4*)bias)[2 * l16 + 1];
        uint4 o;
        o.x = pack_bf16x2(acc[0] * inv + b0.x, acc[1] * inv + b0.y);
        o.y = pack_bf16x2(acc[2] * inv + b0.z, acc[3] * inv + b0.w);
        o.z = pack_bf16x2(acc[4] * inv + b1.x, acc[5] * inv + b1.y);
        o.w = pack_bf16x2(acc[6] * inv + b1.z, acc[7] * inv + b1.w);
        ((uint4*)(hagg + (size_t)d * 64))[l16] = o;
    }
}

// ---------------------------------------------------------------------------
// BN column sums / sums-of-squares over bf16 [N,128]
// ---------------------------------------------------------------------------
__global__ void k_bnstats(const uint* __restrict__ hagg, int N,
                          float* __restrict__ sums, float* __restrict__ sumsq) {
    int t = threadIdx.x;
    int cg = t & 31, rs = t >> 5;
    float4 s = make_float4(0.f, 0.f, 0.f, 0.f), q = make_float4(0.f, 0.f, 0.f, 0.f);
    for (int n = blockIdx.x * 8 + rs; n < N; n += gridDim.x * 8) {
        uint2 u = ((const uint2*)(hagg + (size_t)n * 64))[cg];
        float v0 = bflo(u.x), v1 = bfhi(u.x), v2 = bflo(u.y), v3 = bfhi(u.y);
        s.x += v0; s.y += v1; s.z += v2; s.w += v3;
        q.x += v0 * v0; q.y += v1 * v1; q.z += v2 * v2; q.w += v3 * v3;
    }
    __shared__ float4 ls[256], lq[256];
    ls[t] = s; lq[t] = q;
    __syncthreads();
    if (t < 32) {
        float4 S = ls[t], Q = lq[t];
        for (int r = 1; r < 8; r++) {
            float4 a = ls[t + r * 32], b = lq[t + r * 32];
            S.x += a.x; S.y += a.y; S.z += a.z; S.w += a.w;
            Q.x += b.x; Q.y += b.y; Q.z += b.z; Q.w += b.w;
        }
        atomicAdd(&sums[t * 4 + 0], S.x);
        atomicAdd(&sums[t * 4 + 1], S.y);
        atomicAdd(&sums[t * 4 + 2], S.z);
        atomicAdd(&sums[t * 4 + 3], S.w);
        atomicAdd(&sumsq[t * 4 + 0], Q.x);
        atomicAdd(&sumsq[t * 4 + 1], Q.y);
        atomicAdd(&sumsq[t * 4 + 2], Q.z);
        atomicAdd(&sumsq[t * 4 + 3], Q.w);
    }
}

// ---------------------------------------------------------------------------
// Per LUT node: BN + ReLU + MLP 128->32 (leaky 0.01) -> 1
// ---------------------------------------------------------------------------
__global__ void k_mlp(const uint* __restrict__ hagg, const int* __restrict__ lut,
                      const float* __restrict__ sums, const float* __restrict__ sumsq,
                      const float* __restrict__ gamma, const float* __restrict__ beta,
                      const float* __restrict__ W1, const float* __restrict__ b1,
                      const float* __restrict__ W2, const float* __restrict__ b2,
                      float* __restrict__ out, int N, int nlut) {
    int blk = blockIdx.x;
    if (blk >= nlut) return;
    int node = lut[blk];
    int lane = threadIdx.x;  // 64
    __shared__ float v[128];
    float invN = 1.f / (float)N;
    uint u = hagg[(size_t)node * 64 + lane];
    int c0 = 2 * lane, c1 = 2 * lane + 1;
    {
        float mean = sums[c0] * invN;
        float var = sumsq[c0] * invN - mean * mean;
        float val = (bflo(u) - mean) / sqrtf(var + 1e-5f) * gamma[c0] + beta[c0];
        v[c0] = fmaxf(val, 0.f);
        mean = sums[c1] * invN;
        var = sumsq[c1] * invN - mean * mean;
        val = (bfhi(u) - mean) / sqrtf(var + 1e-5f) * gamma[c1] + beta[c1];
        v[c1] = fmaxf(val, 0.f);
    }
    __syncthreads();
    float r = 0.f;
    if (lane < 32) {
        float z = b1[lane];
        for (int c = 0; c < 128; c++) z += v[c] * W1[c * 32 + lane];
        z = z > 0.f ? z : 0.01f * z;
        r = z * W2[lane];
    }
#pragma unroll
    for (int off = 16; off >= 1; off >>= 1) r += __shfl_xor(r, off);
    if (lane == 0) out[blk] = r + b2[0];
}

// ---------------------------------------------------------------------------
extern "C" void kernel_launch(void* const* d_in, const int* in_sizes, int n_in,
                              void* d_out, int out_size, void* d_ws, size_t ws_size,
                              hipStream_t stream) {
    const float* x     = (const float*)d_in[0];
    const int*   edges = (const int*)d_in[1];
    const int*   lut   = (const int*)d_in[2];
    const float* W_lin = (const float*)d_in[3];
    const float* att_s = (const float*)d_in[4];
    const float* att_d = (const float*)d_in[5];
    const float* bias  = (const float*)d_in[6];
    const float* gamma = (const float*)d_in[7];
    const float* beta  = (const float*)d_in[8];
    const float* W1    = (const float*)d_in[9];
    const float* b1    = (const float*)d_in[10];
    const float* W2    = (const float*)d_in[11];
    const float* b2    = (const float*)d_in[12];

    int N = in_sizes[0] / 16;
    int E = in_sizes[1] / 2;
    int nlut = in_sizes[2];
    int B = (N + 511) >> BSHIFT;

    const int* esrc = edges;
    const int* edst = edges + E;

    char* ws = (char*)d_ws;
    size_t off = 0;
    auto alloc = [&](size_t bytes) -> void* {
        void* p = ws + off;
        off += (bytes + 255) & ~(size_t)255;
        return p;
    };
    uint*  h       = (uint*)alloc((size_t)N * 64 * 4);   // bf16x2 [N,128]
    uint*  hagg    = (uint*)alloc((size_t)N * 64 * 4);   // bf16x2 [N,128]
    float* a_src   = (float*)alloc((size_t)N * 4 * 4);
    float* a_dst   = (float*)alloc((size_t)N * 4 * 4);
    int*   offsets = (int*)alloc((size_t)(N + 1) * 4);
    int*   sorted  = (int*)alloc((size_t)E * 4);
    uint*  pairs   = (uint*)alloc((size_t)E * 4);
    int*   bbase   = (int*)alloc((size_t)(MAXB + 1) * 4);
    int*   cursor  = (int*)alloc((size_t)MAXB * 4);
    int*   bcnt    = (int*)alloc((size_t)MAXB * 4);
    float* sums    = (float*)alloc(128 * 4);
    float* sumsq   = (float*)alloc(128 * 4);
    int*   done    = (int*)alloc(256);

    k_linear<<<(N + 3) / 4, 256, 0, stream>>>(x, W_lin, att_s, att_d, h, a_src, a_dst, N,
                                              bcnt, sums, sumsq, done);
    kb_count<<<256, 256, 0, stream>>>(edst, E, B, bcnt, done, bbase, cursor);
    kb_scatter<<<(E + TILE - 1) / TILE, SCAT_T, 0, stream>>>(esrc, edst, E, cursor, pairs);
    kb_sort<<<B, SORT_T, 0, stream>>>(pairs, bbase, N, E, sorted, offsets);
    k_gat<<<(N + 3) / 4, 256, 0, stream>>>(offsets, sorted, h, a_src, a_dst, bias, hagg, N);
    k_bnstats<<<256, 256, 0, stream>>>(hagg, N, sums, sumsq);
    k_mlp<<<nlut, 64, 0, stream>>>(hagg, lut, sums, sumsq, gamma, beta, W1, b1, W2, b2,
                                   (float*)d_out, N, nlut);
}